// Round 14
// baseline (138.676 us; speedup 1.0000x reference)
//
#include <hip/hip_runtime.h>
#include <hip/hip_bf16.h>
#include <stdint.h>
#include <math.h>

// B=2, T=2048, D=1024, H=16, DH=64
#define T_SEQ 2048
#define NHEAD 16
#define NBH   32      // B*H
#define BTROW 4096    // B*T

typedef __bf16 bf16_t;
typedef __bf16 bf16x4_t __attribute__((ext_vector_type(4)));
typedef __bf16 bf16x8_t __attribute__((ext_vector_type(8)));
typedef float  f32x4_t  __attribute__((ext_vector_type(4)));

// 0.125 (1/sqrt(64)) * log2(e) — folded into Q so softmax uses exp2 directly
#define QSCALE 0.18033688011112042f

__device__ __forceinline__ f32x4_t mfma16(bf16x8_t a, bf16x8_t b, f32x4_t c) {
  return __builtin_amdgcn_mfma_f32_16x16x32_bf16(a, b, c, 0, 0, 0);
}

__device__ __forceinline__ float fast_exp2(float x) {
#if __has_builtin(__builtin_amdgcn_exp2f)
  return __builtin_amdgcn_exp2f(x);
#else
  return exp2f(x);
#endif
}

// async global->LDS, 16B per lane; lds dest is wave-uniform base (HW adds lane*16)
__device__ __forceinline__ void gl_lds16(const bf16_t* g, bf16_t* l) {
  __builtin_amdgcn_global_load_lds(
      (const __attribute__((address_space(1))) void*)g,
      (__attribute__((address_space(3))) void*)l, 16, 0, 0);
}

// Paired-row swizzled GEMM tile: (r, k8) -> lds[ldsrow=r>>1][g], 128B LDS rows,
// g = (((r&1)<<2)|k8) ^ (ldsrow&7). Fragment reads land 2 lanes/bank-group (free).
__device__ __forceinline__ int tile_off(int r, int k8) {  // bf16 element offset
  int lr = r >> 1;
  int g = (((r & 1) << 2) | k8) ^ (lr & 7);
  return lr * 64 + g * 8;
}
// inverse map for staging: linear dest chunk c -> (row, k8) in the source
__device__ __forceinline__ int src_off(int c, int K) {
  int lr = c >> 3;
  int gsrc = (c & 7) ^ (lr & 7);
  int row = (lr << 1) | (gsrc >> 2), kb = gsrc & 3;
  return row * K + kb * 8;
}

// ---------------- fused prep: cast + 2x transpose-cast + rope table ----------------
__device__ __forceinline__ void trans_tile(const float* __restrict__ W,
                                           bf16_t* __restrict__ WT,
                                           int K, int N, int n0, int k0,
                                           float (*tile)[33], int tid) {
  int tx = tid & 31, ty = tid >> 5;  // 32 x 8
#pragma unroll
  for (int j = 0; j < 4; j++)
    tile[ty + j * 8][tx] = W[(size_t)(k0 + ty + j * 8) * N + n0 + tx];
  __syncthreads();
#pragma unroll
  for (int j = 0; j < 4; j++)
    WT[(size_t)(n0 + ty + j * 8) * K + k0 + tx] = (bf16_t)tile[tx][ty + j * 8];
}

__global__ __launch_bounds__(256) void k_prep(const float* __restrict__ x,
                                              const float* __restrict__ Wqkv,
                                              const float* __restrict__ Wout,
                                              bf16_t* __restrict__ xb,
                                              bf16_t* __restrict__ wqkvT,
                                              bf16_t* __restrict__ woutT,
                                              float* __restrict__ cs,
                                              float* __restrict__ sn) {
  __shared__ float tile[32][33];
  int blk = blockIdx.x, tid = threadIdx.x;
  if (blk < 2048) {
    const int n = 4096 * 1024, stride = 2048 * 256;
    for (int i = (blk * 256 + tid) * 4; i < n; i += stride * 4) {
      float4 a = *(const float4*)(x + i);
      bf16x4_t r = { (bf16_t)a.x, (bf16_t)a.y, (bf16_t)a.z, (bf16_t)a.w };
      *(bf16x4_t*)(xb + i) = r;
    }
  } else if (blk < 5120) {
    int bb = blk - 2048;  // 96 x 32 tiles (N=3072, K=1024)
    trans_tile(Wqkv, wqkvT, 1024, 3072, (bb % 96) * 32, (bb / 96) * 32, tile, tid);
  } else if (blk < 6144) {
    int bb = blk - 5120;  // 32 x 32 tiles (N=1024, K=1024)
    trans_tile(Wout, woutT, 1024, 1024, (bb % 32) * 32, (bb / 32) * 32, tile, tid);
  } else {
    int i = (blk - 6144) * 256 + tid;  // t*32 + j, 65536 total
    int t = i >> 5, j = i & 31;
    float inv = powf(10000.0f, -(float)(2 * j) / 64.0f);
    float f = (float)t * inv;
    cs[i] = cosf(f);
    sn[i] = sinf(f);
  }
}

// ---------------- fused QKV GEMM + RoPE + V-transpose ----------------
// 3-buffer counted-vmcnt pipeline; 3x-unrolled body with LITERAL buffer index.
__global__ __launch_bounds__(256) void k_gemm_qkv(const bf16_t* __restrict__ A,
                                                  const bf16_t* __restrict__ Bt,
                                                  const float* __restrict__ cs,
                                                  const float* __restrict__ sn,
                                                  bf16_t* __restrict__ Qr,
                                                  bf16_t* __restrict__ Kr,
                                                  bf16_t* __restrict__ Vt) {
  const int K = 1024, NT = 32;
  __shared__ __align__(16) unsigned char smem[49152];
  bf16_t* vtile = (bf16_t*)smem;

  int m0 = blockIdx.y * 128, n0 = blockIdx.x * 128;
  int tid = threadIdx.x;
  int lane = tid & 63, w = tid >> 6;
  int wr = w >> 1, wc = w & 1;
  int l15 = lane & 15, l4 = lane >> 4;

  f32x4_t acc[4][4];
#pragma unroll
  for (int m = 0; m < 4; m++)
#pragma unroll
    for (int n = 0; n < 4; n++) acc[m][n] = (f32x4_t){0.f, 0.f, 0.f, 0.f};

  const bf16_t* Ag = A + (size_t)m0 * K;
  const bf16_t* Bg = Bt + (size_t)n0 * K;
  int soff0 = src_off(tid, K), soff1 = src_off(256 + tid, K);
  int dst0 = w * 512, dst1 = 2048 + w * 512;
  int afo[4], bfo[4];
#pragma unroll
  for (int m = 0; m < 4; m++) afo[m] = tile_off(wr * 64 + m * 16 + l15, l4);
#pragma unroll
  for (int n = 0; n < 4; n++) bfo[n] = tile_off(wc * 64 + n * 16 + l15, l4);

  auto stageg = [&](int bufbyte, int k0) {
    bf16_t* As = (bf16_t*)(smem + bufbyte);
    bf16_t* Bs = (bf16_t*)(smem + 8192 + bufbyte);
    gl_lds16(Ag + soff0 + k0, As + dst0);
    gl_lds16(Bg + soff0 + k0, Bs + dst0);
    gl_lds16(Ag + soff1 + k0, As + dst1);
    gl_lds16(Bg + soff1 + k0, Bs + dst1);
  };

#define QKV_BODY(KT, CB)                                                          \
  {                                                                               \
    if ((KT) + 1 < NT) asm volatile("s_waitcnt vmcnt(4)" ::: "memory");           \
    else               asm volatile("s_waitcnt vmcnt(0)" ::: "memory");           \
    __builtin_amdgcn_s_barrier();                                                 \
    if ((KT) + 2 < NT) stageg((((CB) + 2) % 3) * 16384, ((KT) + 2) * 32);         \
    const bf16_t* As = (const bf16_t*)(smem + (CB) * 16384);                      \
    const bf16_t* Bs = (const bf16_t*)(smem + 8192 + (CB) * 16384);               \
    bf16x8_t af[4], bfr[4];                                                       \
    _Pragma("unroll")                                                             \
    for (int m = 0; m < 4; m++) af[m] = *(const bf16x8_t*)(As + afo[m]);          \
    _Pragma("unroll")                                                             \
    for (int n = 0; n < 4; n++) bfr[n] = *(const bf16x8_t*)(Bs + bfo[n]);         \
    _Pragma("unroll")                                                             \
    for (int m = 0; m < 4; m++)                                                   \
      _Pragma("unroll")                                                           \
      for (int n = 0; n < 4; n++) acc[m][n] = mfma16(af[m], bfr[n], acc[m][n]);   \
  }

  stageg(0, 0);
  stageg(16384, 32);
  for (int kt0 = 0; kt0 < 30; kt0 += 3) {
    QKV_BODY(kt0 + 0, 0)
    QKV_BODY(kt0 + 1, 1)
    QKV_BODY(kt0 + 2, 2)
  }
  QKV_BODY(30, 0)
  QKV_BODY(31, 1)
#undef QKV_BODY
  __syncthreads();

  int region = n0 >> 10;  // 0=Q, 1=K, 2=V
  if (region < 2) {
    bf16_t* dst = region ? Kr : Qr;
    float qs = region ? 1.0f : QSCALE;
    int h = ((n0 & 1023) + wc * 64) >> 6;
#pragma unroll
    for (int m = 0; m < 4; m++)
#pragma unroll
      for (int r = 0; r < 4; r++) {
        int row = m0 + wr * 64 + m * 16 + l4 * 4 + r;
        int b = row >> 11, t = row & 2047;
        size_t obase = ((size_t)(b * NHEAD + h) * T_SEQ + t) * 64;
#pragma unroll
        for (int n = 0; n < 2; n++) {
          int j = n * 16 + l15;
          float c = cs[t * 32 + j], s = sn[t * 32 + j];
          float x1 = acc[m][n][r], x2 = acc[m][n + 2][r];
          dst[obase + j]      = (bf16_t)((x1 * c - x2 * s) * qs);
          dst[obase + 32 + j] = (bf16_t)((x1 * s + x2 * c) * qs);
        }
      }
  } else {
    // V: stage C-tile into LDS transposed, then coalesced store to Vt[bh][d][t]
#pragma unroll
    for (int m = 0; m < 4; m++)
#pragma unroll
      for (int n = 0; n < 4; n++)
#pragma unroll
        for (int r = 0; r < 4; r++)
          vtile[(size_t)(wc * 64 + n * 16 + l15) * 132 + wr * 64 + m * 16 + l4 * 4 + r] =
              (bf16_t)acc[m][n][r];
    __syncthreads();
    int colbase = n0 - 2048;
    int b = m0 >> 11, t0l = m0 & 2047;
#pragma unroll
    for (int p = 0; p < 64; p++) {
      int idx = p * 256 + tid;
      int dl = idx >> 7, tl = idx & 127;
      int col = colbase + dl, h = col >> 6, d = col & 63;
      Vt[((size_t)(b * NHEAD + h) * 64 + d) * T_SEQ + t0l + tl] = vtile[(size_t)dl * 132 + tl];
    }
  }
}

// ---------------- GEMM2: out[4096][1024] = Ob @ woutT^T, fp32 out ----------------
// 3-buffer counted-vmcnt + XCD swizzle (each XCD gets 64 contiguous blocks = 8 A-panels).
__global__ __launch_bounds__(256) void k_gemm2(const bf16_t* __restrict__ A,
                                               const bf16_t* __restrict__ Bt,
                                               float* __restrict__ C) {
  const int N = 1024, K = 1024, NT = 32;
  __shared__ __align__(16) unsigned char smem[36864];  // 3 x (A 4KB + B 8KB)
  int flat = blockIdx.x;
  int swz = (flat & 7) * 64 + (flat >> 3);
  int m0 = (swz >> 3) * 64, n0 = (swz & 7) * 128;
  int tid = threadIdx.x;
  int lane = tid & 63, w = tid >> 6;
  int l15 = lane & 15, l4 = lane >> 4;

  f32x4_t acc[4][2];
#pragma unroll
  for (int m = 0; m < 4; m++)
#pragma unroll
    for (int n = 0; n < 2; n++) acc[m][n] = (f32x4_t){0.f, 0.f, 0.f, 0.f};

  const bf16_t* Ag = A + (size_t)m0 * K;
  const bf16_t* Bg = Bt + (size_t)n0 * K;
  int soff0 = src_off(tid, K), soff1 = src_off(256 + tid, K);
  int dstA = w * 512, dstB0 = w * 512, dstB1 = 2048 + w * 512;
  int afo[4], bfo[2];
#pragma unroll
  for (int m = 0; m < 4; m++) afo[m] = tile_off(m * 16 + l15, l4);
#pragma unroll
  for (int n = 0; n < 2; n++) bfo[n] = tile_off(w * 32 + n * 16 + l15, l4);

  auto stageg = [&](int bufbyte, int k0) {
    bf16_t* As = (bf16_t*)(smem + bufbyte);
    bf16_t* Bs = (bf16_t*)(smem + 4096 + bufbyte);
    gl_lds16(Ag + soff0 + k0, As + dstA);
    gl_lds16(Bg + soff0 + k0, Bs + dstB0);
    gl_lds16(Bg + soff1 + k0, Bs + dstB1);
  };

#define G2_BODY(KT, CB)                                                           \
  {                                                                               \
    if ((KT) + 1 < NT) asm volatile("s_waitcnt vmcnt(3)" ::: "memory");           \
    else               asm volatile("s_waitcnt vmcnt(0)" ::: "memory");           \
    __builtin_amdgcn_s_barrier();                                                 \
    if ((KT) + 2 < NT) stageg((((CB) + 2) % 3) * 12288, ((KT) + 2) * 32);         \
    const bf16_t* As = (const bf16_t*)(smem + (CB) * 12288);                      \
    const bf16_t* Bs = (const bf16_t*)(smem + 4096 + (CB) * 12288);               \
    bf16x8_t af[4], bfr[2];                                                       \
    _Pragma("unroll")                                                             \
    for (int m = 0; m < 4; m++) af[m] = *(const bf16x8_t*)(As + afo[m]);          \
    _Pragma("unroll")                                                             \
    for (int n = 0; n < 2; n++) bfr[n] = *(const bf16x8_t*)(Bs + bfo[n]);         \
    _Pragma("unroll")                                                             \
    for (int m = 0; m < 4; m++)                                                   \
      _Pragma("unroll")                                                           \
      for (int n = 0; n < 2; n++) acc[m][n] = mfma16(af[m], bfr[n], acc[m][n]);   \
  }

  stageg(0, 0);
  stageg(12288, 32);
  for (int kt0 = 0; kt0 < 30; kt0 += 3) {
    G2_BODY(kt0 + 0, 0)
    G2_BODY(kt0 + 1, 1)
    G2_BODY(kt0 + 2, 2)
  }
  G2_BODY(30, 0)
  G2_BODY(31, 1)
#undef G2_BODY

#pragma unroll
  for (int m = 0; m < 4; m++)
#pragma unroll
    for (int n = 0; n < 2; n++)
#pragma unroll
      for (int r = 0; r < 4; r++) {
        int row = m0 + m * 16 + l4 * 4 + r;
        int col = n0 + w * 32 + n * 16 + l15;
        C[(size_t)row * N + col] = acc[m][n][r];
      }
}

// ---------------- flash attention (split-KV pair, 8 waves, V direct-from-L2) ------
// LDS-BW was the binder (~274 B/cy vs 256 peak). V no longer goes through LDS:
// each wave loads its V fragments straight from global Vt (L2-resident, per-XCD
// working set ~1MB < 4MB). LDS now: Ks (single-buffered, 16KB) + Ps (16KB) = 32KB;
// per block-iter LDS traffic drops 192KB -> ~112KB.
// Per iter: [issue V global loads] -> QK from Ks -> B1 -> stage K(i+1) ->
// mask/softmax/Ps -> PV (vfr) -> vmcnt(0) -> B2.
__global__ __launch_bounds__(512, 4) void k_attn(const bf16_t* __restrict__ Qr,
                                                 const bf16_t* __restrict__ Kr,
                                                 const bf16_t* __restrict__ Vt,
                                                 bf16_t* __restrict__ Ob) {
  __shared__ __align__(16) unsigned char sm[32768];
  bf16_t* Ks = (bf16_t*)sm;            // [2 group-tiles][64*64] = 16KB
  char* PsB = (char*)(sm + 16384);     // 8 waves x 2KB
  int flat = blockIdx.x;
  int swz = (flat & 7) * 64 + (flat >> 3);  // XCD-contiguous bh groups
  int pair = swz & 15, bh = swz >> 4;
  int b = bh >> 4, h = bh & 15;
  int tid = threadIdx.x, lane = tid & 63, w = tid >> 6;
  int grp = w >> 2, wl = w & 3;
  int l15 = lane & 15, l4 = lane >> 4;

  const bf16_t* Kbh = Kr + (size_t)bh * T_SEQ * 64;
  const bf16_t* Vbh = Vt + (size_t)bh * 64 * T_SEQ;

  int srow = tid >> 3;
  int sk8 = (tid & 7) ^ (srow & 7);

  auto stageK = [&](int i) {  // K tiles {2i, 2i+1} -> Ks[0..1] (single-buffered)
#pragma unroll
    for (int tp = 0; tp < 2; tp++) {
      int kb = (2 * i + tp) * 64;
      gl_lds16(Kbh + (size_t)(kb + srow) * 64 + sk8 * 8, Ks + tp * 4096 + (size_t)w * 512);
    }
  };

  char* myPs = PsB + w * 2048;

  // per-(n,ks) V base offsets: Vbh + (n*16+l15)*T_SEQ + ks*32 + l4*8  (+ kb at use)
  const bf16_t* vbase[8];
#pragma unroll
  for (int ks = 0; ks < 2; ks++)
#pragma unroll
    for (int n = 0; n < 4; n++)
      vbase[ks * 4 + n] = Vbh + (size_t)(n * 16 + l15) * T_SEQ + ks * 32 + l4 * 8;

  bf16x8_t ones;
#pragma unroll
  for (int i = 0; i < 8; i++) ones[i] = (bf16_t)1.0f;

  for (int pass = 0; pass < 2; pass++) {
    int qb = pass ? (31 - pair) : pair;
    int q0 = qb * 64;
    int niter = (qb + 2) >> 1;  // ceil((qb+1)/2)

    bf16x8_t qf[2];
    size_t qbase = ((size_t)bh * T_SEQ + q0 + wl * 16 + l15) * 64;
    qf[0] = *(const bf16x8_t*)(Qr + qbase + l4 * 8);
    qf[1] = *(const bf16x8_t*)(Qr + qbase + 32 + l4 * 8);

    f32x4_t o[4];
#pragma unroll
    for (int n = 0; n < 4; n++) o[n] = (f32x4_t){0.f, 0.f, 0.f, 0.f};
    f32x4_t ls = (f32x4_t){0.f, 0.f, 0.f, 0.f};
    float m_s = -1e30f;

    stageK(0);
    asm volatile("s_waitcnt vmcnt(0)" ::: "memory");
    __builtin_amdgcn_s_barrier();

    for (int i = 0; i < niter; i++) {
      int t = 2 * i + grp;  // my group's KV tile
      bool act = (t <= qb);
      int kb = t * 64;

      f32x4_t s[4];
      bf16x8_t vfr[8];
      if (act) {
        // V fragments direct from global (L2) — issued first, consumed in PV
#pragma unroll
        for (int j = 0; j < 8; j++) vfr[j] = *(const bf16x8_t*)(vbase[j] + kb);

        // QK from single-buffered Ks
        const bf16_t* Kt = Ks + grp * 4096;
        __builtin_amdgcn_s_setprio(1);
#pragma unroll
        for (int n = 0; n < 4; n++) {
          int rowK = n * 16 + l15;
          const bf16_t* kp = Kt + (size_t)rowK * 64;
          int sw = rowK & 7;
          bf16x8_t kf0 = *(const bf16x8_t*)(kp + (l4 ^ sw) * 8);
          bf16x8_t kf1 = *(const bf16x8_t*)(kp + ((l4 ^ 4) ^ sw) * 8);
          s[n] = (f32x4_t){0.f, 0.f, 0.f, 0.f};
          s[n] = mfma16(kf0, qf[0], s[n]);
          s[n] = mfma16(kf1, qf[1], s[n]);
        }
        __builtin_amdgcn_s_setprio(0);
      }
      __builtin_amdgcn_s_barrier();  // B1: all waves' QK done -> Ks overwritable

      if (i + 1 < niter) stageK(i + 1);  // prefetch next K pair under softmax+PV

      if (act) {
        if (t == qb) {  // diagonal tile: causal mask
#pragma unroll
          for (int n = 0; n < 4; n++)
#pragma unroll
            for (int r = 0; r < 4; r++)
              if (n * 16 + l4 * 4 + r > wl * 16 + l15) s[n][r] = -1e30f;
        }

        // lane-local max (no shuffles on the common path)
        float t0 = fmaxf(fmaxf(s[0][0], s[0][1]), fmaxf(s[0][2], s[0][3]));
        float t1 = fmaxf(fmaxf(s[1][0], s[1][1]), fmaxf(s[1][2], s[1][3]));
        float t2 = fmaxf(fmaxf(s[2][0], s[2][1]), fmaxf(s[2][2], s[2][3]));
        float t3 = fmaxf(fmaxf(s[3][0], s[3][1]), fmaxf(s[3][2], s[3][3]));
        float mloc = fmaxf(fmaxf(t0, t1), fmaxf(t2, t3));

        // defer-max (T13): full row-max + rescale only on the rare trigger
        if (__any(mloc - m_s > 8.0f)) {
          float mx = fmaxf(mloc, __shfl_xor(mloc, 16, 64));
          mx = fmaxf(mx, __shfl_xor(mx, 32, 64));
          float mnew = fmaxf(m_s, mx);
          float alpha = fast_exp2(m_s - mnew);
          m_s = mnew;
          float ar[4];
#pragma unroll
          for (int r = 0; r < 4; r++) ar[r] = __shfl(alpha, l4 * 4 + r, 64);
#pragma unroll
          for (int n = 0; n < 4; n++)
#pragma unroll
            for (int r = 0; r < 4; r++) o[n][r] *= ar[r];
#pragma unroll
          for (int r = 0; r < 4; r++) ls[r] *= ar[r];
        }

        // P = exp2(S - m), packed to bf16, XOR-swizzled LDS write
#pragma unroll
        for (int n = 0; n < 4; n++) {
#pragma unroll
          for (int r = 0; r < 4; r++) s[n][r] = fast_exp2(s[n][r] - m_s);
          bf16x4_t pk = { (bf16_t)s[n][0], (bf16_t)s[n][1], (bf16_t)s[n][2], (bf16_t)s[n][3] };
          *(bf16x4_t*)(myPs + l15 * 128 +
                       ((((n << 1) | (l4 >> 1)) ^ (l15 & 7)) << 4) + ((l4 & 1) << 3)) = pk;
        }

        // O += P V; l-sum via ones-MFMA
        __builtin_amdgcn_s_setprio(1);
#pragma unroll
        for (int ks = 0; ks < 2; ks++) {
          bf16x8_t pa = *(const bf16x8_t*)(myPs + l15 * 128 +
                                           ((((ks << 2) | l4) ^ (l15 & 7)) << 4));
          ls = mfma16(pa, ones, ls);
#pragma unroll
          for (int n = 0; n < 4; n++) o[n] = mfma16(pa, vfr[ks * 4 + n], o[n]);
        }
        __builtin_amdgcn_s_setprio(0);
      }

      // drain this iter's K prefetch (covered by softmax+PV), then B2
      asm volatile("s_waitcnt vmcnt(0)" ::: "memory");
      __builtin_amdgcn_s_barrier();  // K(i+1) visible for next iter
    }

    // ---- merge group B into group A via LDS (overlays Ks+Ps, 32KB) ----
    __syncthreads();
    float* mg = (float*)sm;  // 4 waves x 64 lanes x 25 f32 = 25.6KB
    int base = (wl * 64 + lane) * 25;
    if (grp == 1) {
#pragma unroll
      for (int n = 0; n < 4; n++)
#pragma unroll
        for (int r = 0; r < 4; r++) mg[base + n * 4 + r] = o[n][r];
#pragma unroll
      for (int r = 0; r < 4; r++) mg[base + 16 + r] = ls[r];
#pragma unroll
      for (int r = 0; r < 4; r++) mg[base + 20 + r] = __shfl(m_s, l4 * 4 + r, 64);
    }
    __syncthreads();
    if (grp == 0) {
#pragma unroll
      for (int r = 0; r < 4; r++) {
        float mA = __shfl(m_s, l4 * 4 + r, 64);
        float mB = mg[base + 20 + r];
        float mF = fmaxf(mA, mB);
        float fA = fast_exp2(mA - mF), fB = fast_exp2(mB - mF);
        float lF = ls[r] * fA + mg[base + 16 + r] * fB;
        float ir = 1.0f / lF;
        int q = q0 + wl * 16 + l4 * 4 + r;
        size_t off = ((size_t)(b * T_SEQ + q)) * 1024 + h * 64;
#pragma unroll
        for (int n = 0; n < 4; n++) {
          float val = o[n][r] * fA + mg[base + n * 4 + r] * fB;
          Ob[off + n * 16 + l15] = (bf16_t)(val * ir);
        }
      }
    }
    __syncthreads();  // protect Ks/Ps before next pass restages
  }
}

// ---------------- launch ----------------
extern "C" void kernel_launch(void* const* d_in, const int* in_sizes, int n_in,
                              void* d_out, int out_size, void* d_ws, size_t ws_size,
                              hipStream_t stream) {
  const float* x    = (const float*)d_in[0];
  const float* Wqkv = (const float*)d_in[1];
  const float* Wout = (const float*)d_in[2];
  float* out = (float*)d_out;
  char* ws = (char*)d_ws;

  bf16_t* wqkvT = (bf16_t*)(ws + 0);                       // [3072][1024] 6 MB
  bf16_t* woutT = (bf16_t*)(ws + 6291456);                 // [1024][1024] 2 MB
  bf16_t* xb    = (bf16_t*)(ws + 8388608);                 // [4096][1024] 8 MB (reused as Ob)
  bf16_t* Qr    = (bf16_t*)(ws + 41943040);                // [32][2048][64] 8 MB
  bf16_t* Kr    = (bf16_t*)(ws + 50331648);                // 8 MB
  bf16_t* Vt    = (bf16_t*)(ws + 58720256);                // [32][64][2048] 8 MB
  float*  cs    = (float*)(ws + 67108864);                 // [2048][32] 256 KB
  float*  sn    = (float*)(ws + 67371008);                 // 256 KB
  bf16_t* Ob    = xb;  // xb dead after GEMM1

  k_prep<<<6400, 256, 0, stream>>>(x, Wqkv, Wout, xb, wqkvT, woutT, cs, sn);
  k_gemm_qkv<<<dim3(3072 / 128, 4096 / 128), 256, 0, stream>>>(xb, wqkvT, cs, sn, Qr, Kr, Vt);
  k_attn<<<512, 512, 0, stream>>>(Qr, Kr, Vt, Ob);
  k_gemm2<<<512, 256, 0, stream>>>(Ob, woutT, out);
}

// Round 15
// 97.769 us; speedup vs baseline: 1.4184x; 1.4184x over previous
//
#include <hip/hip_runtime.h>
#include <hip/hip_bf16.h>
#include <stdint.h>
#include <math.h>

// B=2, T=2048, D=1024, H=16, DH=64
#define T_SEQ 2048
#define NHEAD 16
#define NBH   32      // B*H
#define BTROW 4096    // B*T

typedef __bf16 bf16_t;
typedef __bf16 bf16x4_t __attribute__((ext_vector_type(4)));
typedef __bf16 bf16x8_t __attribute__((ext_vector_type(8)));
typedef float  f32x4_t  __attribute__((ext_vector_type(4)));

// 0.125 (1/sqrt(64)) * log2(e) — folded into Q so softmax uses exp2 directly
#define QSCALE 0.18033688011112042f

__device__ __forceinline__ f32x4_t mfma16(bf16x8_t a, bf16x8_t b, f32x4_t c) {
  return __builtin_amdgcn_mfma_f32_16x16x32_bf16(a, b, c, 0, 0, 0);
}

__device__ __forceinline__ float fast_exp2(float x) {
#if __has_builtin(__builtin_amdgcn_exp2f)
  return __builtin_amdgcn_exp2f(x);
#else
  return exp2f(x);
#endif
}

// async global->LDS, 16B per lane; lds dest is wave-uniform base (HW adds lane*16)
__device__ __forceinline__ void gl_lds16(const bf16_t* g, bf16_t* l) {
  __builtin_amdgcn_global_load_lds(
      (const __attribute__((address_space(1))) void*)g,
      (__attribute__((address_space(3))) void*)l, 16, 0, 0);
}

// Paired-row swizzled GEMM tile: (r, k8) -> lds[ldsrow=r>>1][g], 128B LDS rows,
// g = (((r&1)<<2)|k8) ^ (ldsrow&7). Fragment reads land 2 lanes/bank-group (free).
__device__ __forceinline__ int tile_off(int r, int k8) {  // bf16 element offset
  int lr = r >> 1;
  int g = (((r & 1) << 2) | k8) ^ (lr & 7);
  return lr * 64 + g * 8;
}
// inverse map for staging: linear dest chunk c -> (row, k8) in the source
__device__ __forceinline__ int src_off(int c, int K) {
  int lr = c >> 3;
  int gsrc = (c & 7) ^ (lr & 7);
  int row = (lr << 1) | (gsrc >> 2), kb = gsrc & 3;
  return row * K + kb * 8;
}

// ---------------- fused prep: cast + 2x transpose-cast + rope table ----------------
__device__ __forceinline__ void trans_tile(const float* __restrict__ W,
                                           bf16_t* __restrict__ WT,
                                           int K, int N, int n0, int k0,
                                           float (*tile)[33], int tid) {
  int tx = tid & 31, ty = tid >> 5;  // 32 x 8
#pragma unroll
  for (int j = 0; j < 4; j++)
    tile[ty + j * 8][tx] = W[(size_t)(k0 + ty + j * 8) * N + n0 + tx];
  __syncthreads();
#pragma unroll
  for (int j = 0; j < 4; j++)
    WT[(size_t)(n0 + ty + j * 8) * K + k0 + tx] = (bf16_t)tile[tx][ty + j * 8];
}

__global__ __launch_bounds__(256) void k_prep(const float* __restrict__ x,
                                              const float* __restrict__ Wqkv,
                                              const float* __restrict__ Wout,
                                              bf16_t* __restrict__ xb,
                                              bf16_t* __restrict__ wqkvT,
                                              bf16_t* __restrict__ woutT,
                                              float* __restrict__ cs,
                                              float* __restrict__ sn) {
  __shared__ float tile[32][33];
  int blk = blockIdx.x, tid = threadIdx.x;
  if (blk < 2048) {
    const int n = 4096 * 1024, stride = 2048 * 256;
    for (int i = (blk * 256 + tid) * 4; i < n; i += stride * 4) {
      float4 a = *(const float4*)(x + i);
      bf16x4_t r = { (bf16_t)a.x, (bf16_t)a.y, (bf16_t)a.z, (bf16_t)a.w };
      *(bf16x4_t*)(xb + i) = r;
    }
  } else if (blk < 5120) {
    int bb = blk - 2048;  // 96 x 32 tiles (N=3072, K=1024)
    trans_tile(Wqkv, wqkvT, 1024, 3072, (bb % 96) * 32, (bb / 96) * 32, tile, tid);
  } else if (blk < 6144) {
    int bb = blk - 5120;  // 32 x 32 tiles (N=1024, K=1024)
    trans_tile(Wout, woutT, 1024, 1024, (bb % 32) * 32, (bb / 32) * 32, tile, tid);
  } else {
    int i = (blk - 6144) * 256 + tid;  // t*32 + j, 65536 total
    int t = i >> 5, j = i & 31;
    float inv = powf(10000.0f, -(float)(2 * j) / 64.0f);
    float f = (float)t * inv;
    cs[i] = cosf(f);
    sn[i] = sinf(f);
  }
}

// ---------------- fused QKV GEMM + RoPE + V-transpose ----------------
// 3-buffer counted-vmcnt pipeline; 3x-unrolled body with LITERAL buffer index.
__global__ __launch_bounds__(256) void k_gemm_qkv(const bf16_t* __restrict__ A,
                                                  const bf16_t* __restrict__ Bt,
                                                  const float* __restrict__ cs,
                                                  const float* __restrict__ sn,
                                                  bf16_t* __restrict__ Qr,
                                                  bf16_t* __restrict__ Kr,
                                                  bf16_t* __restrict__ Vt) {
  const int K = 1024, NT = 32;
  __shared__ __align__(16) unsigned char smem[49152];
  bf16_t* vtile = (bf16_t*)smem;

  int m0 = blockIdx.y * 128, n0 = blockIdx.x * 128;
  int tid = threadIdx.x;
  int lane = tid & 63, w = tid >> 6;
  int wr = w >> 1, wc = w & 1;
  int l15 = lane & 15, l4 = lane >> 4;

  f32x4_t acc[4][4];
#pragma unroll
  for (int m = 0; m < 4; m++)
#pragma unroll
    for (int n = 0; n < 4; n++) acc[m][n] = (f32x4_t){0.f, 0.f, 0.f, 0.f};

  const bf16_t* Ag = A + (size_t)m0 * K;
  const bf16_t* Bg = Bt + (size_t)n0 * K;
  int soff0 = src_off(tid, K), soff1 = src_off(256 + tid, K);
  int dst0 = w * 512, dst1 = 2048 + w * 512;
  int afo[4], bfo[4];
#pragma unroll
  for (int m = 0; m < 4; m++) afo[m] = tile_off(wr * 64 + m * 16 + l15, l4);
#pragma unroll
  for (int n = 0; n < 4; n++) bfo[n] = tile_off(wc * 64 + n * 16 + l15, l4);

  auto stageg = [&](int bufbyte, int k0) {
    bf16_t* As = (bf16_t*)(smem + bufbyte);
    bf16_t* Bs = (bf16_t*)(smem + 8192 + bufbyte);
    gl_lds16(Ag + soff0 + k0, As + dst0);
    gl_lds16(Bg + soff0 + k0, Bs + dst0);
    gl_lds16(Ag + soff1 + k0, As + dst1);
    gl_lds16(Bg + soff1 + k0, Bs + dst1);
  };

#define QKV_BODY(KT, CB)                                                          \
  {                                                                               \
    if ((KT) + 1 < NT) asm volatile("s_waitcnt vmcnt(4)" ::: "memory");           \
    else               asm volatile("s_waitcnt vmcnt(0)" ::: "memory");           \
    __builtin_amdgcn_s_barrier();                                                 \
    if ((KT) + 2 < NT) stageg((((CB) + 2) % 3) * 16384, ((KT) + 2) * 32);         \
    const bf16_t* As = (const bf16_t*)(smem + (CB) * 16384);                      \
    const bf16_t* Bs = (const bf16_t*)(smem + 8192 + (CB) * 16384);               \
    bf16x8_t af[4], bfr[4];                                                       \
    _Pragma("unroll")                                                             \
    for (int m = 0; m < 4; m++) af[m] = *(const bf16x8_t*)(As + afo[m]);          \
    _Pragma("unroll")                                                             \
    for (int n = 0; n < 4; n++) bfr[n] = *(const bf16x8_t*)(Bs + bfo[n]);         \
    _Pragma("unroll")                                                             \
    for (int m = 0; m < 4; m++)                                                   \
      _Pragma("unroll")                                                           \
      for (int n = 0; n < 4; n++) acc[m][n] = mfma16(af[m], bfr[n], acc[m][n]);   \
  }

  stageg(0, 0);
  stageg(16384, 32);
  for (int kt0 = 0; kt0 < 30; kt0 += 3) {
    QKV_BODY(kt0 + 0, 0)
    QKV_BODY(kt0 + 1, 1)
    QKV_BODY(kt0 + 2, 2)
  }
  QKV_BODY(30, 0)
  QKV_BODY(31, 1)
#undef QKV_BODY
  __syncthreads();

  int region = n0 >> 10;  // 0=Q, 1=K, 2=V
  if (region < 2) {
    bf16_t* dst = region ? Kr : Qr;
    float qs = region ? 1.0f : QSCALE;
    int h = ((n0 & 1023) + wc * 64) >> 6;
#pragma unroll
    for (int m = 0; m < 4; m++)
#pragma unroll
      for (int r = 0; r < 4; r++) {
        int row = m0 + wr * 64 + m * 16 + l4 * 4 + r;
        int b = row >> 11, t = row & 2047;
        size_t obase = ((size_t)(b * NHEAD + h) * T_SEQ + t) * 64;
#pragma unroll
        for (int n = 0; n < 2; n++) {
          int j = n * 16 + l15;
          float c = cs[t * 32 + j], s = sn[t * 32 + j];
          float x1 = acc[m][n][r], x2 = acc[m][n + 2][r];
          dst[obase + j]      = (bf16_t)((x1 * c - x2 * s) * qs);
          dst[obase + 32 + j] = (bf16_t)((x1 * s + x2 * c) * qs);
        }
      }
  } else {
    // V: stage C-tile into LDS transposed, then coalesced store to Vt[bh][d][t]
#pragma unroll
    for (int m = 0; m < 4; m++)
#pragma unroll
      for (int n = 0; n < 4; n++)
#pragma unroll
        for (int r = 0; r < 4; r++)
          vtile[(size_t)(wc * 64 + n * 16 + l15) * 132 + wr * 64 + m * 16 + l4 * 4 + r] =
              (bf16_t)acc[m][n][r];
    __syncthreads();
    int colbase = n0 - 2048;
    int b = m0 >> 11, t0l = m0 & 2047;
#pragma unroll
    for (int p = 0; p < 64; p++) {
      int idx = p * 256 + tid;
      int dl = idx >> 7, tl = idx & 127;
      int col = colbase + dl, h = col >> 6, d = col & 63;
      Vt[((size_t)(b * NHEAD + h) * 64 + d) * T_SEQ + t0l + tl] = vtile[(size_t)dl * 132 + tl];
    }
  }
}

// ---------------- GEMM2: out[4096][1024] = Ob @ woutT^T, fp32 out ----------------
// 3-buffer counted-vmcnt + XCD swizzle.
__global__ __launch_bounds__(256) void k_gemm2(const bf16_t* __restrict__ A,
                                               const bf16_t* __restrict__ Bt,
                                               float* __restrict__ C) {
  const int N = 1024, K = 1024, NT = 32;
  __shared__ __align__(16) unsigned char smem[36864];  // 3 x (A 4KB + B 8KB)
  int flat = blockIdx.x;
  int swz = (flat & 7) * 64 + (flat >> 3);
  int m0 = (swz >> 3) * 64, n0 = (swz & 7) * 128;
  int tid = threadIdx.x;
  int lane = tid & 63, w = tid >> 6;
  int l15 = lane & 15, l4 = lane >> 4;

  f32x4_t acc[4][2];
#pragma unroll
  for (int m = 0; m < 4; m++)
#pragma unroll
    for (int n = 0; n < 2; n++) acc[m][n] = (f32x4_t){0.f, 0.f, 0.f, 0.f};

  const bf16_t* Ag = A + (size_t)m0 * K;
  const bf16_t* Bg = Bt + (size_t)n0 * K;
  int soff0 = src_off(tid, K), soff1 = src_off(256 + tid, K);
  int dstA = w * 512, dstB0 = w * 512, dstB1 = 2048 + w * 512;
  int afo[4], bfo[2];
#pragma unroll
  for (int m = 0; m < 4; m++) afo[m] = tile_off(m * 16 + l15, l4);
#pragma unroll
  for (int n = 0; n < 2; n++) bfo[n] = tile_off(w * 32 + n * 16 + l15, l4);

  auto stageg = [&](int bufbyte, int k0) {
    bf16_t* As = (bf16_t*)(smem + bufbyte);
    bf16_t* Bs = (bf16_t*)(smem + 4096 + bufbyte);
    gl_lds16(Ag + soff0 + k0, As + dstA);
    gl_lds16(Bg + soff0 + k0, Bs + dstB0);
    gl_lds16(Bg + soff1 + k0, Bs + dstB1);
  };

#define G2_BODY(KT, CB)                                                           \
  {                                                                               \
    if ((KT) + 1 < NT) asm volatile("s_waitcnt vmcnt(3)" ::: "memory");           \
    else               asm volatile("s_waitcnt vmcnt(0)" ::: "memory");           \
    __builtin_amdgcn_s_barrier();                                                 \
    if ((KT) + 2 < NT) stageg((((CB) + 2) % 3) * 12288, ((KT) + 2) * 32);         \
    const bf16_t* As = (const bf16_t*)(smem + (CB) * 12288);                      \
    const bf16_t* Bs = (const bf16_t*)(smem + 4096 + (CB) * 12288);               \
    bf16x8_t af[4], bfr[2];                                                       \
    _Pragma("unroll")                                                             \
    for (int m = 0; m < 4; m++) af[m] = *(const bf16x8_t*)(As + afo[m]);          \
    _Pragma("unroll")                                                             \
    for (int n = 0; n < 2; n++) bfr[n] = *(const bf16x8_t*)(Bs + bfo[n]);         \
    _Pragma("unroll")                                                             \
    for (int m = 0; m < 4; m++)                                                   \
      _Pragma("unroll")                                                           \
      for (int n = 0; n < 2; n++) acc[m][n] = mfma16(af[m], bfr[n], acc[m][n]);   \
  }

  stageg(0, 0);
  stageg(12288, 32);
  for (int kt0 = 0; kt0 < 30; kt0 += 3) {
    G2_BODY(kt0 + 0, 0)
    G2_BODY(kt0 + 1, 1)
    G2_BODY(kt0 + 2, 2)
  }
  G2_BODY(30, 0)
  G2_BODY(31, 1)
#undef G2_BODY

#pragma unroll
  for (int m = 0; m < 4; m++)
#pragma unroll
    for (int n = 0; n < 2; n++)
#pragma unroll
      for (int r = 0; r < 4; r++) {
        int row = m0 + m * 16 + l4 * 4 + r;
        int col = n0 + w * 32 + n * 16 + l15;
        C[(size_t)row * N + col] = acc[m][n][r];
      }
}

// ---------------- flash attention (split-KV pair, 8 waves, 64KB LDS) ----------------
// R13 version (measured best: 39.9us). K single-buffered, V double-buffered in LDS.
// Per iter: QK(i) -> B1 -> stage K(i+1)+V(i+1) -> softmax/P -> PV(i) -> vmcnt(0) -> B2.
__global__ __launch_bounds__(512, 4) void k_attn(const bf16_t* __restrict__ Qr,
                                                 const bf16_t* __restrict__ Kr,
                                                 const bf16_t* __restrict__ Vt,
                                                 bf16_t* __restrict__ Ob) {
  __shared__ __align__(16) bf16_t Ks[2][64 * 64];     // [group tile][] single-buffered
  __shared__ __align__(16) bf16_t Vs[2][2][64 * 64];  // [buf][group tile][]
  __shared__ __align__(16) bf16_t Ps[8][16 * 64];     // per-wave P, XOR-swizzled
  int flat = blockIdx.x;
  int swz = (flat & 7) * 64 + (flat >> 3);  // XCD-contiguous bh groups
  int pair = swz & 15, bh = swz >> 4;
  int b = bh >> 4, h = bh & 15;
  int tid = threadIdx.x, lane = tid & 63, w = tid >> 6;
  int grp = w >> 2, wl = w & 3;
  int l15 = lane & 15, l4 = lane >> 4;

  const bf16_t* Kbh = Kr + (size_t)bh * T_SEQ * 64;
  const bf16_t* Vbh = Vt + (size_t)bh * 64 * T_SEQ;

  int srow = tid >> 3;
  int sk8 = (tid & 7) ^ (srow & 7);

  auto stageK = [&](int i) {
#pragma unroll
    for (int tp = 0; tp < 2; tp++) {
      int kb = (2 * i + tp) * 64;
      gl_lds16(Kbh + (size_t)(kb + srow) * 64 + sk8 * 8, &Ks[tp][0] + (size_t)w * 512);
    }
  };
  auto stageV = [&](int buf, int i) {
#pragma unroll
    for (int tp = 0; tp < 2; tp++) {
      int kb = (2 * i + tp) * 64;
      gl_lds16(Vbh + (size_t)srow * T_SEQ + kb + sk8 * 8, &Vs[buf][tp][0] + (size_t)w * 512);
    }
  };

  char* myPs = (char*)&Ps[w][0];

  bf16x8_t ones;
#pragma unroll
  for (int i = 0; i < 8; i++) ones[i] = (bf16_t)1.0f;

  for (int pass = 0; pass < 2; pass++) {
    int qb = pass ? (31 - pair) : pair;
    int q0 = qb * 64;
    int niter = (qb + 2) >> 1;  // ceil((qb+1)/2)

    bf16x8_t qf[2];
    size_t qbase = ((size_t)bh * T_SEQ + q0 + wl * 16 + l15) * 64;
    qf[0] = *(const bf16x8_t*)(Qr + qbase + l4 * 8);
    qf[1] = *(const bf16x8_t*)(Qr + qbase + 32 + l4 * 8);

    f32x4_t o[4];
#pragma unroll
    for (int n = 0; n < 4; n++) o[n] = (f32x4_t){0.f, 0.f, 0.f, 0.f};
    f32x4_t ls = (f32x4_t){0.f, 0.f, 0.f, 0.f};
    float m_s = -1e30f;

    stageK(0);
    stageV(0, 0);
    asm volatile("s_waitcnt vmcnt(0)" ::: "memory");
    __builtin_amdgcn_s_barrier();

    for (int i = 0; i < niter; i++) {
      int cur = i & 1;
      int t = 2 * i + grp;  // my group's KV tile
      bool act = (t <= qb);

      // ---- QK from single-buffered Ks (ready & visible on entry) ----
      f32x4_t s[4];
      if (act) {
        const bf16_t* Kt = &Ks[grp][0];
        __builtin_amdgcn_s_setprio(1);
#pragma unroll
        for (int n = 0; n < 4; n++) {
          int rowK = n * 16 + l15;
          const bf16_t* kp = Kt + (size_t)rowK * 64;
          int sw = rowK & 7;
          bf16x8_t kf0 = *(const bf16x8_t*)(kp + (l4 ^ sw) * 8);
          bf16x8_t kf1 = *(const bf16x8_t*)(kp + ((l4 ^ 4) ^ sw) * 8);
          s[n] = (f32x4_t){0.f, 0.f, 0.f, 0.f};
          s[n] = mfma16(kf0, qf[0], s[n]);
          s[n] = mfma16(kf1, qf[1], s[n]);
        }
        __builtin_amdgcn_s_setprio(0);
      }
      __builtin_amdgcn_s_barrier();  // B1: all waves' QK done -> Ks overwritable

      if (i + 1 < niter) {           // prefetch next pair under softmax+PV
        stageK(i + 1);
        stageV(cur ^ 1, i + 1);
      }

      if (act) {
        const bf16_t* Vtl = &Vs[cur][grp][0];
        // V fragments issued now — latency hides under the softmax chain
        bf16x8_t vfr[8];
#pragma unroll
        for (int ks = 0; ks < 2; ks++)
#pragma unroll
          for (int n = 0; n < 4; n++) {
            int rowV = n * 16 + l15;
            vfr[ks * 4 + n] = *(const bf16x8_t*)(Vtl + (size_t)rowV * 64 +
                                                 (((ks * 4 + l4) ^ (rowV & 7)) * 8));
          }

        if (t == qb) {  // diagonal tile: causal mask
#pragma unroll
          for (int n = 0; n < 4; n++)
#pragma unroll
            for (int r = 0; r < 4; r++)
              if (n * 16 + l4 * 4 + r > wl * 16 + l15) s[n][r] = -1e30f;
        }

        // lane-local max (no shuffles on the common path)
        float t0 = fmaxf(fmaxf(s[0][0], s[0][1]), fmaxf(s[0][2], s[0][3]));
        float t1 = fmaxf(fmaxf(s[1][0], s[1][1]), fmaxf(s[1][2], s[1][3]));
        float t2 = fmaxf(fmaxf(s[2][0], s[2][1]), fmaxf(s[2][2], s[2][3]));
        float t3 = fmaxf(fmaxf(s[3][0], s[3][1]), fmaxf(s[3][2], s[3][3]));
        float mloc = fmaxf(fmaxf(t0, t1), fmaxf(t2, t3));

        // defer-max (T13): full row-max + rescale only on the rare trigger
        if (__any(mloc - m_s > 8.0f)) {
          float mx = fmaxf(mloc, __shfl_xor(mloc, 16, 64));
          mx = fmaxf(mx, __shfl_xor(mx, 32, 64));
          float mnew = fmaxf(m_s, mx);
          float alpha = fast_exp2(m_s - mnew);
          m_s = mnew;
          float ar[4];
#pragma unroll
          for (int r = 0; r < 4; r++) ar[r] = __shfl(alpha, l4 * 4 + r, 64);
#pragma unroll
          for (int n = 0; n < 4; n++)
#pragma unroll
            for (int r = 0; r < 4; r++) o[n][r] *= ar[r];
#pragma unroll
          for (int r = 0; r < 4; r++) ls[r] *= ar[r];
        }

        // P = exp2(S - m), packed to bf16, XOR-swizzled LDS write
#pragma unroll
        for (int n = 0; n < 4; n++) {
#pragma unroll
          for (int r = 0; r < 4; r++) s[n][r] = fast_exp2(s[n][r] - m_s);
          bf16x4_t pk = { (bf16_t)s[n][0], (bf16_t)s[n][1], (bf16_t)s[n][2], (bf16_t)s[n][3] };
          *(bf16x4_t*)(myPs + l15 * 128 +
                       ((((n << 1) | (l4 >> 1)) ^ (l15 & 7)) << 4) + ((l4 & 1) << 3)) = pk;
        }

        // O += P V; l-sum via ones-MFMA
        __builtin_amdgcn_s_setprio(1);
#pragma unroll
        for (int ks = 0; ks < 2; ks++) {
          bf16x8_t pa = *(const bf16x8_t*)(myPs + l15 * 128 +
                                           ((((ks << 2) | l4) ^ (l15 & 7)) << 4));
          ls = mfma16(pa, ones, ls);
#pragma unroll
          for (int n = 0; n < 4; n++) o[n] = mfma16(pa, vfr[ks * 4 + n], o[n]);
        }
        __builtin_amdgcn_s_setprio(0);
      }

      // drain this iter's prefetch (covered by ~500cy of softmax+PV), then B2
      asm volatile("s_waitcnt vmcnt(0)" ::: "memory");
      __builtin_amdgcn_s_barrier();  // K(i+1)/V(i+1) visible; Vs[cur] free next iter
    }

    // ---- merge group B into group A via LDS (overlays dead Vs area, 32KB) ----
    __syncthreads();
    float* mg = (float*)&Vs[0][0][0];  // 4 waves x 64 lanes x 25 f32 = 25.6KB
    int base = (wl * 64 + lane) * 25;
    if (grp == 1) {
#pragma unroll
      for (int n = 0; n < 4; n++)
#pragma unroll
        for (int r = 0; r < 4; r++) mg[base + n * 4 + r] = o[n][r];
#pragma unroll
      for (int r = 0; r < 4; r++) mg[base + 16 + r] = ls[r];
#pragma unroll
      for (int r = 0; r < 4; r++) mg[base + 20 + r] = __shfl(m_s, l4 * 4 + r, 64);
    }
    __syncthreads();
    if (grp == 0) {
#pragma unroll
      for (int r = 0; r < 4; r++) {
        float mA = __shfl(m_s, l4 * 4 + r, 64);
        float mB = mg[base + 20 + r];
        float mF = fmaxf(mA, mB);
        float fA = fast_exp2(mA - mF), fB = fast_exp2(mB - mF);
        float lF = ls[r] * fA + mg[base + 16 + r] * fB;
        float ir = 1.0f / lF;
        int q = q0 + wl * 16 + l4 * 4 + r;
        size_t off = ((size_t)(b * T_SEQ + q)) * 1024 + h * 64;
#pragma unroll
        for (int n = 0; n < 4; n++) {
          float val = o[n][r] * fA + mg[base + n * 4 + r] * fB;
          Ob[off + n * 16 + l15] = (bf16_t)(val * ir);
        }
      }
    }
    __syncthreads();  // protect Ks/Vs/Ps before next pass restages
  }
}

// ---------------- launch ----------------
extern "C" void kernel_launch(void* const* d_in, const int* in_sizes, int n_in,
                              void* d_out, int out_size, void* d_ws, size_t ws_size,
                              hipStream_t stream) {
  const float* x    = (const float*)d_in[0];
  const float* Wqkv = (const float*)d_in[1];
  const float* Wout = (const float*)d_in[2];
  float* out = (float*)d_out;
  char* ws = (char*)d_ws;

  bf16_t* wqkvT = (bf16_t*)(ws + 0);                       // [3072][1024] 6 MB
  bf16_t* woutT = (bf16_t*)(ws + 6291456);                 // [1024][1024] 2 MB
  bf16_t* xb    = (bf16_t*)(ws + 8388608);                 // [4096][1024] 8 MB (reused as Ob)
  bf16_t* Qr    = (bf16_t*)(ws + 41943040);                // [32][2048][64] 8 MB
  bf16_t* Kr    = (bf16_t*)(ws + 50331648);                // 8 MB
  bf16_t* Vt    = (bf16_t*)(ws + 58720256);                // [32][64][2048] 8 MB
  float*  cs    = (float*)(ws + 67108864);                 // [2048][32] 256 KB
  float*  sn    = (float*)(ws + 67371008);                 // 256 KB
  bf16_t* Ob    = xb;  // xb dead after GEMM1

  k_prep<<<6400, 256, 0, stream>>>(x, Wqkv, Wout, xb, wqkvT, woutT, cs, sn);
  k_gemm_qkv<<<dim3(3072 / 128, 4096 / 128), 256, 0, stream>>>(xb, wqkvT, cs, sn, Qr, Kr, Vt);
  k_attn<<<512, 512, 0, stream>>>(Qr, Kr, Vt, Ob);
  k_gemm2<<<512, 256, 0, stream>>>(Ob, woutT, out);
}